// Round 5
// baseline (325.525 us; speedup 1.0000x reference)
//
#include <hip/hip_runtime.h>

// Problem constants
#define QN    2048
#define SS    8
#define DD    2048
#define SP    100
#define NCLS  20
#define MROWS (QN*SS)       // 16384 GEMM M
#define NREAL (SP*SS)       // 800 real support rows
#define NPAD  1024          // padded N: 4 full 256-tiles, uniform grid
#define KK    DD
#define BK    64
#define NTK   (KK/BK)       // 32 K-tiles

typedef __bf16 bf16x8 __attribute__((ext_vector_type(8)));
typedef float  f32x4  __attribute__((ext_vector_type(4)));

__device__ __forceinline__ unsigned short f2bf(float f) {
    unsigned int u = __float_as_uint(f);
    u += 0x7fffu + ((u >> 16) & 1u);   // round-to-nearest-even
    return (unsigned short)(u >> 16);
}

// ---------------- Kernel 1: fp32 -> bf16 + row L2 norms + out zeroing + B pad zeroing ----
// One WAVE per row. 4 rows per 256-thread block.
__global__ void cvt_kernel(const float* __restrict__ tf, const float* __restrict__ sf,
                           unsigned short* __restrict__ Abf, unsigned short* __restrict__ Bbf,
                           float* __restrict__ nA, float* __restrict__ nB,
                           float* __restrict__ out)
{
    // zero the logits output (gemm accumulates atomically): 160*256 = 40960 elems
    if (blockIdx.x < 160) out[blockIdx.x * 256 + threadIdx.x] = 0.f;

    const int wv   = threadIdx.x >> 6;
    const int lane = threadIdx.x & 63;
    const int row  = blockIdx.x * 4 + wv;       // 0 .. 17407

    const float* src;
    unsigned short* dst;
    float* nrm; int r;
    if (row < MROWS) { src = tf + (size_t)row * DD; dst = Abf + (size_t)row * DD; nrm = nA; r = row; }
    else {
        r = row - MROWS;                        // 0..1023
        if (r >= NREAL) {                       // pad rows: zero-fill so GEMM acc is exactly 0
            unsigned short* d2 = Bbf + (size_t)r * DD;
            ushort4 z = make_ushort4(0, 0, 0, 0);
#pragma unroll
            for (int j = 0; j < 8; ++j) *(ushort4*)(d2 + j * 256 + lane * 4) = z;
            if (lane == 0) nB[r] = 0.f;
            return;
        }
        src = sf + (size_t)r * DD; dst = Bbf + (size_t)r * DD; nrm = nB;
    }

    float s = 0.f;
#pragma unroll
    for (int j = 0; j < 8; j++) {
        float4 v = *(const float4*)(src + j * 256 + lane * 4);
        s += v.x*v.x + v.y*v.y + v.z*v.z + v.w*v.w;
        ushort4 pk = make_ushort4(f2bf(v.x), f2bf(v.y), f2bf(v.z), f2bf(v.w));
        *(ushort4*)(dst + j * 256 + lane * 4) = pk;
    }
#pragma unroll
    for (int o = 32; o; o >>= 1) s += __shfl_down(s, o);
    if (lane == 0) nrm[r] = sqrtf(s);
}

// ---------------- softmin helpers ----------------
__device__ __forceinline__ float softmin2(float a, float b) {
    float mn = fminf(a, b), mx = fmaxf(a, b);
    return mn - 0.1f * __logf(1.0f + __expf((mn - mx) * 10.0f));
}
__device__ __forceinline__ float softmin3(float a, float b, float c) {
    float mn = fminf(fminf(a, b), c);
    float sum = __expf((mn - a) * 10.0f) + __expf((mn - b) * 10.0f) + __expf((mn - c) * 10.0f);
    return mn - 0.1f * __logf(sum);
}

__device__ __forceinline__ void gld16(const void* g, void* l) {
    __builtin_amdgcn_global_load_lds(
        (const __attribute__((address_space(1))) unsigned int*)g,
        (__attribute__((address_space(3))) unsigned int*)l, 16, 0, 0);
}

// bf16 cell (a,b) of lane's 8x8 tile held in 8 uint4 registers -> fp32
__device__ __forceinline__ float cellf(const uint4* raw, int a, int b) {
    const unsigned* p = (const unsigned*)raw;
    unsigned wv = p[a * 4 + (b >> 1)];
    return __uint_as_float((b & 1) ? (wv & 0xffff0000u) : (wv << 16));
}

// OTAM DP over the lane's 8x8 tile (dir selects transpose), returns final cost
__device__ __forceinline__ float otam_dp(const uint4* raw, int dir) {
    float prev[10], cur[10];
    prev[0] = 0.f;
#pragma unroll
    for (int m = 1; m <= 8; m++) {
        float v0 = cellf(raw, 0, m - 1), v1 = cellf(raw, m - 1, 0);
        prev[m] = prev[m - 1] + (dir ? v1 : v0);
    }
    prev[9] = prev[8];
#pragma unroll
    for (int l = 1; l < 8; l++) {
        float d[8];
#pragma unroll
        for (int j = 0; j < 8; j++) {
            float v0 = cellf(raw, l, j), v1 = cellf(raw, j, l);
            d[j] = dir ? v1 : v0;
        }
        cur[1] = d[0] + softmin3(prev[0], prev[1], 0.0f);
#pragma unroll
        for (int m = 2; m <= 8; m++)
            cur[m] = d[m - 1] + softmin2(prev[m - 1], cur[m - 1]);
        cur[9] = softmin3(prev[8], prev[9], cur[8]);   // pad column: d=0
#pragma unroll
        for (int m = 1; m < 10; m++) prev[m] = cur[m];
    }
    return prev[9];
}

// ---------------- K-tile body: register-pipelined, every cluster's operands read >=1
// cluster (~600 cyc) before consumption, so LDS read service hides under MFMA execution.
//
//   [entry: af0 (A-lo k0), bf0 (B k0) of CB already in registers]
//   stage B(t+1)+A-lo(t+1)->NB ; read af1,bf1 (k1)      ; cluster A: acc[0-3]+=af0*bf0
//   vmcnt(6)+barrier [A-hi(t) valid]
//   stage A-hi(t+1)->NB        ; read af2,af3 (A-hi)    ; cluster B: acc[0-3]+=af1*bf1
//                                                       ; cluster C: acc[4-7]+=af2*bf0
//   vmcnt(2)+barrier [B+A-lo(t+1) valid; A-hi(t+1) in flight]
//   pre-read af0',bf0' from NB (next tile k0)           ; cluster D: acc[4-7]+=af3*bf1
//
// Hazards: all CB ds_reads complete before the boundary barrier (cluster D operand waits);
// staging into NB(t)=CB(t-1) is issued only after boundary(t-1). A-hi reads sit after the
// mid barrier (A-hi(t) drained by vmcnt(6): 6 = this tile's B+A-lo loads). Pre-read touches
// only NB regions drained by vmcnt(2). Accumulation order per acc unchanged (k0 then k1).
template<int CB>
__device__ __forceinline__ void tile_body(
    char* lds8, f32x4 (&acc)[8][4],
    bf16x8 (&af0)[4], bf16x8 (&bf0)[4],          // pre-loaded k0 fragments of CB
    const unsigned short* sA, const unsigned short* sB,
    const int t, const int arow, const int brow, const int sb16, const int stoff)
{
    constexpr int NB = CB ^ 65536;
    const bool st = (t + 1 < NTK);
    const int t1 = (t + 1) * BK;        // shorts
    bf16x8 af1[4], af2[4], af3[4], bf1[4];

    // ---- stage B(t+1) x4 + A-lo(t+1) x2 into NB (the 6 youngest VMEM ops) ----
    if (st) {
        gld16(sB + t1,                    lds8 + NB + 32768 + stoff);
        gld16(sB + (size_t) 64 * KK + t1, lds8 + NB + 32768 +  8192 + stoff);
        gld16(sB + (size_t)128 * KK + t1, lds8 + NB + 32768 + 16384 + stoff);
        gld16(sB + (size_t)192 * KK + t1, lds8 + NB + 32768 + 24576 + stoff);
        gld16(sA + t1,                    lds8 + NB + stoff);
        gld16(sA + (size_t)128 * KK + t1, lds8 + NB + 16384 + stoff);
    }

    // ---- read k1 fragments (A-lo + B) from CB; consumed by cluster B ----
#pragma unroll
    for (int i = 0; i < 4; ++i)
        af1[i] = *(const bf16x8*)(lds8 + CB + arow + i * 2048 + (sb16 ^ 64));
#pragma unroll
    for (int n = 0; n < 4; ++n)
        bf1[n] = *(const bf16x8*)(lds8 + CB + brow + n * 2048 + (sb16 ^ 64));

    // ---- cluster A: acc[0-3] += af0*bf0 (operands pre-read last tile) ----
    __builtin_amdgcn_s_setprio(1);
#pragma unroll
    for (int mi = 0; mi < 4; ++mi)
#pragma unroll
        for (int n = 0; n < 4; ++n)
            acc[mi][n] = __builtin_amdgcn_mfma_f32_16x16x32_bf16(af0[mi], bf0[n], acc[mi][n], 0, 0, 0);
    __builtin_amdgcn_s_setprio(0);

    // ---- mid-tile: validate A-hi(t); leftover in flight = B(t+1)x4 + A-lo(t+1)x2 ----
    if (st) asm volatile("s_waitcnt vmcnt(6)");
    else    asm volatile("s_waitcnt vmcnt(0)");
    __builtin_amdgcn_s_barrier();

    // ---- stage A-hi(t+1) x2 into NB ----
    if (st) {
        gld16(sA + (size_t) 64 * KK + t1, lds8 + NB +  8192 + stoff);
        gld16(sA + (size_t)192 * KK + t1, lds8 + NB + 24576 + stoff);
    }

    // ---- read A-hi fragments (k0 for cluster C, k1 for cluster D) ----
#pragma unroll
    for (int i = 0; i < 4; ++i)
        af2[i] = *(const bf16x8*)(lds8 + CB + arow + 8192 + i * 2048 + sb16);
#pragma unroll
    for (int i = 0; i < 4; ++i)
        af3[i] = *(const bf16x8*)(lds8 + CB + arow + 8192 + i * 2048 + (sb16 ^ 64));

    // ---- cluster B: acc[0-3] += af1*bf1 (read one cluster ago) ----
    __builtin_amdgcn_s_setprio(1);
#pragma unroll
    for (int mi = 0; mi < 4; ++mi)
#pragma unroll
        for (int n = 0; n < 4; ++n)
            acc[mi][n] = __builtin_amdgcn_mfma_f32_16x16x32_bf16(af1[mi], bf1[n], acc[mi][n], 0, 0, 0);
    __builtin_amdgcn_s_setprio(0);

    // ---- cluster C: acc[4-7] += af2*bf0 (af2 read one cluster ago) ----
    __builtin_amdgcn_s_setprio(1);
#pragma unroll
    for (int mi = 0; mi < 4; ++mi)
#pragma unroll
        for (int n = 0; n < 4; ++n)
            acc[4 + mi][n] = __builtin_amdgcn_mfma_f32_16x16x32_bf16(af2[mi], bf0[n], acc[4 + mi][n], 0, 0, 0);
    __builtin_amdgcn_s_setprio(0);

    // ---- boundary: B(t+1)+A-lo(t+1) valid in NB; A-hi(t+1) stays in flight ----
    if (st) asm volatile("s_waitcnt vmcnt(2)");
    __builtin_amdgcn_s_barrier();

    // ---- pre-read next tile's k0 fragments from NB (consumed by next cluster A) ----
    if (st) {
#pragma unroll
        for (int i = 0; i < 4; ++i)
            af0[i] = *(const bf16x8*)(lds8 + NB + arow + i * 2048 + sb16);
#pragma unroll
        for (int n = 0; n < 4; ++n)
            bf0[n] = *(const bf16x8*)(lds8 + NB + brow + n * 2048 + sb16);
    }

    // ---- cluster D: acc[4-7] += af3*bf1 (af3 read two clusters ago) ----
    __builtin_amdgcn_s_setprio(1);
#pragma unroll
    for (int mi = 0; mi < 4; ++mi)
#pragma unroll
        for (int n = 0; n < 4; ++n)
            acc[4 + mi][n] = __builtin_amdgcn_mfma_f32_16x16x32_bf16(af3[mi], bf1[n], acc[4 + mi][n], 0, 0, 0);
    __builtin_amdgcn_s_setprio(0);
}

// ======================= Kernel 2: 256x256 fused GEMM + DP ==============================
// 8 waves (2M x 4N), BK=64, double-buffered 128 KiB LDS, XOR-swizzled A/B tiles,
// counted vmcnt, 2 barriers per K-tile, register-pipelined fragment reads.
__global__ __launch_bounds__(512, 2) void gemm_kernel(
    const unsigned short* __restrict__ A,   // [MROWS][K] bf16 bits
    const unsigned short* __restrict__ B,   // [NPAD][K]  bf16 bits (rows >=800 zeroed)
    const float* __restrict__ nA, const float* __restrict__ nB,
    const int* __restrict__ labels,
    float* __restrict__ out)                // [QN][NCLS], zeroed by cvt
{
    extern __shared__ __align__(16) char lds8[];   // 131072 B dynamic

    const int mt   = blockIdx.x;            // 0..63
    const int nt   = blockIdx.y;            // 0..3
    const int tid  = threadIdx.x;
    const int lane = tid & 63;
    const int w    = tid >> 6;              // 0..7
    const int wm   = w >> 2, wn = w & 3;    // 2 x 4 wave grid
    const int col  = lane & 15, kg = lane >> 4;
    const int mbase = mt * 256, nbase = nt * 256;

    // ---- staging addressing (pre-swizzled global source, linear LDS dest) ----
    const int ks8 = ((lane & 7) ^ (lane >> 3)) << 3;                 // shorts
    const unsigned short* sA = A + (size_t)(mbase + w * 8 + (lane >> 3)) * KK + ks8;
    const unsigned short* sB = B + (size_t)(nbase + w * 8 + (lane >> 3)) * KK + ks8;
    const int stoff = w * 1024 + lane * 16;                          // bytes, linear per wave

    // ---- ds_read addressing (swizzled) ----
    const int sb16 = ((kg ^ (col & 7)) << 4);                        // phys slot*16 for kk=0
    const int arow = (wm * 128 + col) * 128;                         // A frag row base (bytes)
    const int brow = 32768 + (wn * 64 + col) * 128;                  // B frag row base (bytes)

    f32x4 acc[8][4] = {};
    bf16x8 af0[4], bf0[4];

    // ---- prologue: stage tile 0 into buffer 0 (8 loads), drain once, pre-read k0 ----
    gld16(sB,                       lds8 + 32768 + stoff);           // B rows   0- 63
    gld16(sB + (size_t) 64 * KK,    lds8 + 32768 +  8192 + stoff);   // B rows  64-127
    gld16(sB + (size_t)128 * KK,    lds8 + 32768 + 16384 + stoff);   // B rows 128-191
    gld16(sB + (size_t)192 * KK,    lds8 + 32768 + 24576 + stoff);   // B rows 192-255
    gld16(sA,                       lds8 + stoff);                   // A rows   0- 63 (lo)
    gld16(sA + (size_t)128 * KK,    lds8 + 16384 + stoff);           // A rows 128-191 (lo)
    gld16(sA + (size_t) 64 * KK,    lds8 +  8192 + stoff);           // A rows  64-127 (hi)
    gld16(sA + (size_t)192 * KK,    lds8 + 24576 + stoff);           // A rows 192-255 (hi)
    asm volatile("s_waitcnt vmcnt(0)");
    __builtin_amdgcn_s_barrier();
#pragma unroll
    for (int i = 0; i < 4; ++i)
        af0[i] = *(const bf16x8*)(lds8 + arow + i * 2048 + sb16);
#pragma unroll
    for (int n = 0; n < 4; ++n)
        bf0[n] = *(const bf16x8*)(lds8 + brow + n * 2048 + sb16);

    for (int t = 0; t < NTK; t += 2) {
        tile_body<0>    (lds8, acc, af0, bf0, sA, sB, t,     arow, brow, sb16, stoff);
        tile_body<65536>(lds8, acc, af0, bf0, sA, sB, t + 1, arow, brow, sb16, stoff);
    }

    // ======================= fused epilogue: cos-dist -> OTAM DP -> class mean ===========
    __syncthreads();
    unsigned short* eb = (unsigned short*)lds8 + w * 2304;   // 32 rows x 64 cols, stride 72
    const int pr  = lane & 31;
    const int qv2 = pr >> 3, sv = pr & 7;
    const int dir = lane >> 5;

#pragma unroll
    for (int p = 0; p < 4; ++p) {
        if (p) __syncthreads();
#pragma unroll
        for (int mi2 = 0; mi2 < 2; ++mi2) {
            const int mi = p * 2 + mi2;
            float nx[4];
#pragma unroll
            for (int r = 0; r < 4; ++r) nx[r] = nA[mbase + wm * 128 + mi * 16 + kg * 4 + r];
#pragma unroll
            for (int ni = 0; ni < 4; ++ni) {
                const float ny = nB[nbase + wn * 64 + ni * 16 + col];
#pragma unroll
                for (int r = 0; r < 4; ++r) {
                    float d = 1.0f - acc[mi][ni][r] * __builtin_amdgcn_rcpf(nx[r] * ny + 0.01f);
                    eb[(mi2 * 16 + kg * 4 + r) * 72 + ni * 16 + col] = f2bf(d);
                }
            }
        }
        __syncthreads();

        uint4 raw[8];
        const unsigned short* tb = eb + (qv2 * 8) * 72 + sv * 8;
#pragma unroll
        for (int l = 0; l < 8; ++l) raw[l] = *(const uint4*)(tb + l * 72);

        float res = otam_dp(raw, dir);
        res += __shfl_down(res, 32);
        if (dir == 0) {
            const int sg = nt * 32 + wn * 8 + sv;
            if (sg < SP) {
                const int qg = mt * 32 + wm * 16 + p * 4 + qv2;
                atomicAdd(out + (size_t)qg * NCLS + labels[sg], -res * 0.2f);
            }
        }
    }
}

// ---------------- launch ----------------
extern "C" void kernel_launch(void* const* d_in, const int* in_sizes, int n_in,
                              void* d_out, int out_size, void* d_ws, size_t ws_size,
                              hipStream_t stream)
{
    const float* tf     = (const float*)d_in[0];   // [2048,8,2048] f32
    const float* sf     = (const float*)d_in[1];   // [100,8,2048]  f32
    const int*   labels = (const int*)d_in[2];     // [100] i32
    float* out = (float*)d_out;                    // [1,2048,20] f32

    char* ws = (char*)d_ws;
    const size_t szA    = (size_t)MROWS * KK * 2;      // 67108864
    const size_t szB    = (size_t)NPAD  * KK * 2;      // 4194304
    const size_t szNA   = (size_t)MROWS * 4;           // 65536
    unsigned short* Abf = (unsigned short*)ws;
    unsigned short* Bbf = (unsigned short*)(ws + szA);
    float* nA   = (float*)(ws + szA + szB);
    float* nB   = (float*)(ws + szA + szB + szNA);

    static int inited = 0;
    if (!inited) {
        (void)hipFuncSetAttribute((const void*)gemm_kernel,
                                  hipFuncAttributeMaxDynamicSharedMemorySize, 131072);
        inited = 1;
    }

    cvt_kernel<<<(MROWS + NPAD) / 4, 256, 0, stream>>>(tf, sf, Abf, Bbf, nA, nB, out);
    gemm_kernel<<<dim3(MROWS / 256, NPAD / 256), 512, 131072, stream>>>(Abf, Bbf, nA, nB, labels, out);
}

// Round 6
// 289.731 us; speedup vs baseline: 1.1235x; 1.1235x over previous
//
#include <hip/hip_runtime.h>

// Problem constants
#define QN    2048
#define SS    8
#define DD    2048
#define SP    100
#define NCLS  20
#define MROWS (QN*SS)       // 16384 GEMM M
#define NREAL (SP*SS)       // 800 real support rows
#define NPAD  1024          // padded N
#define KK    DD
#define BK    32
#define NTK   (KK/BK)       // 64 K-tiles
#define BUF   24576         // bytes per LDS buffer: A 8192 + B 16384
#define LDSZ  (3*BUF)       // 73728

typedef __bf16 bf16x8 __attribute__((ext_vector_type(8)));
typedef float  f32x4  __attribute__((ext_vector_type(4)));

__device__ __forceinline__ unsigned short f2bf(float f) {
    unsigned int u = __float_as_uint(f);
    u += 0x7fffu + ((u >> 16) & 1u);   // round-to-nearest-even
    return (unsigned short)(u >> 16);
}

// ---------------- Kernel 1: fp32 -> bf16 + row L2 norms + out zeroing + B pad zeroing ----
__global__ void cvt_kernel(const float* __restrict__ tf, const float* __restrict__ sf,
                           unsigned short* __restrict__ Abf, unsigned short* __restrict__ Bbf,
                           float* __restrict__ nA, float* __restrict__ nB,
                           float* __restrict__ out)
{
    if (blockIdx.x < 160) out[blockIdx.x * 256 + threadIdx.x] = 0.f;

    const int wv   = threadIdx.x >> 6;
    const int lane = threadIdx.x & 63;
    const int row  = blockIdx.x * 4 + wv;       // 0 .. 17407

    const float* src;
    unsigned short* dst;
    float* nrm; int r;
    if (row < MROWS) { src = tf + (size_t)row * DD; dst = Abf + (size_t)row * DD; nrm = nA; r = row; }
    else {
        r = row - MROWS;                        // 0..1023
        if (r >= NREAL) {                       // pad rows: zero-fill so GEMM acc is exactly 0
            unsigned short* d2 = Bbf + (size_t)r * DD;
            ushort4 z = make_ushort4(0, 0, 0, 0);
#pragma unroll
            for (int j = 0; j < 8; ++j) *(ushort4*)(d2 + j * 256 + lane * 4) = z;
            if (lane == 0) nB[r] = 0.f;
            return;
        }
        src = sf + (size_t)r * DD; dst = Bbf + (size_t)r * DD; nrm = nB;
    }

    float s = 0.f;
#pragma unroll
    for (int j = 0; j < 8; j++) {
        float4 v = *(const float4*)(src + j * 256 + lane * 4);
        s += v.x*v.x + v.y*v.y + v.z*v.z + v.w*v.w;
        ushort4 pk = make_ushort4(f2bf(v.x), f2bf(v.y), f2bf(v.z), f2bf(v.w));
        *(ushort4*)(dst + j * 256 + lane * 4) = pk;
    }
#pragma unroll
    for (int o = 32; o; o >>= 1) s += __shfl_down(s, o);
    if (lane == 0) nrm[r] = sqrtf(s);
}

// ---------------- softmin helpers ----------------
__device__ __forceinline__ float softmin2(float a, float b) {
    float mn = fminf(a, b), mx = fmaxf(a, b);
    return mn - 0.1f * __logf(1.0f + __expf((mn - mx) * 10.0f));
}
__device__ __forceinline__ float softmin3(float a, float b, float c) {
    float mn = fminf(fminf(a, b), c);
    float sum = __expf((mn - a) * 10.0f) + __expf((mn - b) * 10.0f) + __expf((mn - c) * 10.0f);
    return mn - 0.1f * __logf(sum);
}

__device__ __forceinline__ void gld16(const void* g, void* l) {
    __builtin_amdgcn_global_load_lds(
        (const __attribute__((address_space(1))) unsigned int*)g,
        (__attribute__((address_space(3))) unsigned int*)l, 16, 0, 0);
}

// bf16 cell (a,b) of lane's 8x8 tile held in 8 uint4 registers -> fp32
__device__ __forceinline__ float cellf(const uint4* raw, int a, int b) {
    const unsigned* p = (const unsigned*)raw;
    unsigned wv = p[a * 4 + (b >> 1)];
    return __uint_as_float((b & 1) ? (wv & 0xffff0000u) : (wv << 16));
}

// OTAM DP over the lane's 8x8 tile (dir selects transpose), returns final cost
__device__ __forceinline__ float otam_dp(const uint4* raw, int dir) {
    float prev[10], cur[10];
    prev[0] = 0.f;
#pragma unroll
    for (int m = 1; m <= 8; m++) {
        float v0 = cellf(raw, 0, m - 1), v1 = cellf(raw, m - 1, 0);
        prev[m] = prev[m - 1] + (dir ? v1 : v0);
    }
    prev[9] = prev[8];
#pragma unroll
    for (int l = 1; l < 8; l++) {
        float d[8];
#pragma unroll
        for (int j = 0; j < 8; j++) {
            float v0 = cellf(raw, l, j), v1 = cellf(raw, j, l);
            d[j] = dir ? v1 : v0;
        }
        cur[1] = d[0] + softmin3(prev[0], prev[1], 0.0f);
#pragma unroll
        for (int m = 2; m <= 8; m++)
            cur[m] = d[m - 1] + softmin2(prev[m - 1], cur[m - 1]);
        cur[9] = softmin3(prev[8], prev[9], cur[8]);   // pad column: d=0
#pragma unroll
        for (int m = 1; m < 10; m++) prev[m] = cur[m];
    }
    return prev[9];
}

// ---------------- K-tile body: triple-buffered, 1 barrier/tile, 2-tile prefetch ---------
// CB = consume buffer base; SB = stage buffer base (for tile t+2).
// Steady state per wave: 3 loads in flight for t+1 + 3 issued for t+2 = 6;
// vmcnt(3) at tile end drains t+1's (deadline next tile), keeps t+2's in flight
// (slack ~2 tiles > HBM latency). Overwrite hazard: SB(t) = CB(t-1)? No:
// SB = (t+2)%3, CB(t-1) = (t-1)%3 = (t+2)%3 -> staged buffer was fully read at t-1,
// and our loads are issued after t-1's end barrier. Safe.
template<int CB, int SB>
__device__ __forceinline__ void tile_body(
    char* lds8, f32x4 (&acc)[4][4],
    const unsigned short* sA, const unsigned short* sB0, const unsigned short* sB1,
    const int t, const int abase, const int bbase,
    const int stA, const int stB0, const int stB1)
{
    const bool st = (t + 2) < NTK;
    const int tS = (t + 2) * BK;        // shorts
    if (st) {
        gld16(sA  + tS, lds8 + SB + stA);
        gld16(sB0 + tS, lds8 + SB + stB0);
        gld16(sB1 + tS, lds8 + SB + stB1);
    }
    bf16x8 bf[4];
#pragma unroll
    for (int n = 0; n < 4; ++n)
        bf[n] = *(const bf16x8*)(lds8 + CB + bbase + n * 1024);
    __builtin_amdgcn_s_setprio(1);
#pragma unroll
    for (int mi = 0; mi < 4; ++mi) {
        bf16x8 af = *(const bf16x8*)(lds8 + CB + abase + mi * 1024);
#pragma unroll
        for (int n = 0; n < 4; ++n)
            acc[mi][n] = __builtin_amdgcn_mfma_f32_16x16x32_bf16(af, bf[n], acc[mi][n], 0, 0, 0);
    }
    __builtin_amdgcn_s_setprio(0);
    if (st)                 asm volatile("s_waitcnt vmcnt(3)");   // t+1's data landed
    else if (t + 1 < NTK)   asm volatile("s_waitcnt vmcnt(0)");   // tail: drain last tile
    __builtin_amdgcn_s_barrier();
}

// ======================= Kernel 2: 128x256 fused GEMM + DP, 2 blocks/CU =================
// 8 waves (2M x 4N, 64x64 per wave), BK=32, TRIPLE-buffered 72 KiB LDS -> 2 independent
// blocks per CU (4 waves/SIMD across 2 barrier domains): block Y's MFMA covers block X's
// read burst + barrier. VGPR forced <=128 via __launch_bounds__(512,4).
__global__ __launch_bounds__(512, 4) void gemm_kernel(
    const unsigned short* __restrict__ A,   // [MROWS][K] bf16 bits
    const unsigned short* __restrict__ B,   // [NPAD][K]  bf16 bits (rows >=800 zeroed)
    const float* __restrict__ nA, const float* __restrict__ nB,
    const int* __restrict__ labels,
    float* __restrict__ out)                // [QN][NCLS], zeroed by cvt
{
    extern __shared__ __align__(16) char lds8[];   // 73728 B dynamic

    const int mt   = blockIdx.x;            // 0..127
    const int nt   = blockIdx.y;            // 0..3
    const int tid  = threadIdx.x;
    const int lane = tid & 63;
    const int w    = tid >> 6;              // 0..7
    const int wm   = w >> 2, wn = w & 3;    // 2 x 4 wave grid, per-wave 64x64
    const int col  = lane & 15, kg = lane >> 4;   // kg 0..3 = k-slot (BK=32 = 4 x 8 bf16)
    const int mbase = mt * 128, nbase = nt * 256;

    // ---- staging (pre-swizzled global source, linear LDS dest) ----
    // chunk c covers LDS byte c*16: row = c>>2, phys slot = c&3,
    // logical kslot = (c&3) ^ ((c>>3)&3)  [= phys ^ ((row>>1)&3), both-sides consistent]
    const int srow = tid >> 2;                                   // 0..127
    const int sks  = ((tid & 3) ^ ((tid >> 3) & 3)) << 3;        // shorts
    const unsigned short* sA  = A + (size_t)(mbase + srow) * KK + sks;
    const unsigned short* sB0 = B + (size_t)(nbase + srow) * KK + sks;        // B rows 0-127
    const unsigned short* sB1 = B + (size_t)(nbase + 128 + srow) * KK + sks;  // B rows 128-255
    const int stA  = tid * 16;              // byte offsets within a buffer
    const int stB0 = 8192  + tid * 16;
    const int stB1 = 16384 + tid * 16;

    // ---- ds_read addressing (swizzled; rows are 64 B, 4 x 16B slots) ----
    // phys = kg ^ ((row>>1)&3); row = base+col with base%64==0 and +16*mi steps -> term
    // depends only on col, so one base per operand + imm offsets.
    const int arow0 = wm * 64 + col;
    const int abase = arow0 * 64 + ((kg ^ ((col >> 1) & 3)) << 4);
    const int brow0 = wn * 64 + col;
    const int bbase = 8192 + brow0 * 64 + ((kg ^ ((col >> 1) & 3)) << 4);

    f32x4 acc[4][4] = {};

    // ---- prologue: stage tiles 0 (buf0) and 1 (buf1); drain tile 0 ----
    gld16(sA,       lds8 + stA);  gld16(sB0,       lds8 + stB0);  gld16(sB1,       lds8 + stB1);
    gld16(sA + BK,  lds8 + BUF + stA); gld16(sB0 + BK, lds8 + BUF + stB0); gld16(sB1 + BK, lds8 + BUF + stB1);
    asm volatile("s_waitcnt vmcnt(3)");
    __builtin_amdgcn_s_barrier();

    for (int t = 0; t < NTK - 1; t += 3) {
        tile_body<0,     2*BUF>(lds8, acc, sA, sB0, sB1, t,     abase, bbase, stA, stB0, stB1);
        tile_body<BUF,   0    >(lds8, acc, sA, sB0, sB1, t + 1, abase, bbase, stA, stB0, stB1);
        tile_body<2*BUF, BUF  >(lds8, acc, sA, sB0, sB1, t + 2, abase, bbase, stA, stB0, stB1);
    }
    tile_body<0, 2*BUF>(lds8, acc, sA, sB0, sB1, NTK - 1, abase, bbase, stA, stB0, stB1);

    // ======================= fused epilogue: cos-dist -> OTAM DP -> class mean ===========
    // per wave: 64x64 output in two 32-row passes; eb 32 rows x 64 cols stride 72
    unsigned short* eb = (unsigned short*)lds8 + w * 2304;
    const int pr  = lane & 31;
    const int qv2 = pr >> 3, sv = pr & 7;
    const int dir = lane >> 5;

#pragma unroll
    for (int p = 0; p < 2; ++p) {
        if (p) __syncthreads();
#pragma unroll
        for (int mi2 = 0; mi2 < 2; ++mi2) {
            const int mi = p * 2 + mi2;
            float nx[4];
#pragma unroll
            for (int r = 0; r < 4; ++r) nx[r] = nA[mbase + wm * 64 + mi * 16 + kg * 4 + r];
#pragma unroll
            for (int ni = 0; ni < 4; ++ni) {
                const float ny = nB[nbase + wn * 64 + ni * 16 + col];
#pragma unroll
                for (int r = 0; r < 4; ++r) {
                    float d = 1.0f - acc[mi][ni][r] * __builtin_amdgcn_rcpf(nx[r] * ny + 0.01f);
                    eb[(mi2 * 16 + kg * 4 + r) * 72 + ni * 16 + col] = f2bf(d);
                }
            }
        }
        __syncthreads();

        uint4 raw[8];
        const unsigned short* tb = eb + (qv2 * 8) * 72 + sv * 8;
#pragma unroll
        for (int l = 0; l < 8; ++l) raw[l] = *(const uint4*)(tb + l * 72);

        float res = otam_dp(raw, dir);
        res += __shfl_down(res, 32);
        if (dir == 0) {
            const int sg = nt * 32 + wn * 8 + sv;
            if (sg < SP) {
                const int qg = mt * 16 + wm * 8 + p * 4 + qv2;
                atomicAdd(out + (size_t)qg * NCLS + labels[sg], -res * 0.2f);
            }
        }
    }
}

// ---------------- launch ----------------
extern "C" void kernel_launch(void* const* d_in, const int* in_sizes, int n_in,
                              void* d_out, int out_size, void* d_ws, size_t ws_size,
                              hipStream_t stream)
{
    const float* tf     = (const float*)d_in[0];   // [2048,8,2048] f32
    const float* sf     = (const float*)d_in[1];   // [100,8,2048]  f32
    const int*   labels = (const int*)d_in[2];     // [100] i32
    float* out = (float*)d_out;                    // [1,2048,20] f32

    char* ws = (char*)d_ws;
    const size_t szA    = (size_t)MROWS * KK * 2;      // 67108864
    const size_t szB    = (size_t)NPAD  * KK * 2;      // 4194304
    const size_t szNA   = (size_t)MROWS * 4;           // 65536
    unsigned short* Abf = (unsigned short*)ws;
    unsigned short* Bbf = (unsigned short*)(ws + szA);
    float* nA   = (float*)(ws + szA + szB);
    float* nB   = (float*)(ws + szA + szB + szNA);

    static int inited = 0;
    if (!inited) {
        (void)hipFuncSetAttribute((const void*)gemm_kernel,
                                  hipFuncAttributeMaxDynamicSharedMemorySize, LDSZ);
        inited = 1;
    }

    cvt_kernel<<<(MROWS + NPAD) / 4, 256, 0, stream>>>(tf, sf, Abf, Bbf, nA, nB, out);
    gemm_kernel<<<dim3(MROWS / 128, NPAD / 256), 512, LDSZ, stream>>>(Abf, Bbf, nA, nB, labels, out);
}

// Round 7
// 289.523 us; speedup vs baseline: 1.1243x; 1.0007x over previous
//
#include <hip/hip_runtime.h>

// Problem constants
#define QN    2048
#define SS    8
#define DD    2048
#define SP    100
#define NCLS  20
#define MROWS (QN*SS)       // 16384 GEMM M
#define NROWS (SP*SS)       // 800   logical N
#define NPAD  800           // no padding: 6 full 128-tiles + one 32-wide tail
#define KK    DD

typedef __bf16 bf16x8 __attribute__((ext_vector_type(8)));
typedef float  f32x4  __attribute__((ext_vector_type(4)));

__device__ __forceinline__ unsigned short f2bf(float f) {
    unsigned int u = __float_as_uint(f);
    u += 0x7fffu + ((u >> 16) & 1u);   // round-to-nearest-even
    return (unsigned short)(u >> 16);
}

// ---------------- Kernel 1: fp32 -> bf16 + row L2 norms + out zeroing ----------------
// One WAVE per row (no barriers, no LDS). 4 rows per 256-thread block.
__global__ void cvt_kernel(const float* __restrict__ tf, const float* __restrict__ sf,
                           unsigned short* __restrict__ Abf, unsigned short* __restrict__ Bbf,
                           float* __restrict__ nA, float* __restrict__ nB,
                           float* __restrict__ out)
{
    // zero the logits output (gemm accumulates atomically): 160*256 = 40960 elems
    if (blockIdx.x < 160) out[blockIdx.x * 256 + threadIdx.x] = 0.f;

    const int wv   = threadIdx.x >> 6;
    const int lane = threadIdx.x & 63;
    const int row  = blockIdx.x * 4 + wv;       // 0 .. 17183

    const float* src;
    unsigned short* dst;
    float* nrm; int r;
    if (row < MROWS) { src = tf + (size_t)row * DD; dst = Abf + (size_t)row * DD; nrm = nA; r = row; }
    else {
        r = row - MROWS;                        // 0..799, all real
        src = sf + (size_t)r * DD; dst = Bbf + (size_t)r * DD; nrm = nB;
    }

    float s = 0.f;
#pragma unroll
    for (int j = 0; j < 8; j++) {
        float4 v = *(const float4*)(src + j * 256 + lane * 4);
        s += v.x*v.x + v.y*v.y + v.z*v.z + v.w*v.w;
        ushort4 pk = make_ushort4(f2bf(v.x), f2bf(v.y), f2bf(v.z), f2bf(v.w));
        *(ushort4*)(dst + j * 256 + lane * 4) = pk;
    }
#pragma unroll
    for (int o = 32; o; o >>= 1) s += __shfl_down(s, o);
    if (lane == 0) nrm[r] = sqrtf(s);
}

// ---------------- softmin helpers ----------------
__device__ __forceinline__ float softmin2(float a, float b) {
    float mn = fminf(a, b), mx = fmaxf(a, b);
    return mn - 0.1f * __logf(1.0f + __expf((mn - mx) * 10.0f));
}
__device__ __forceinline__ float softmin3(float a, float b, float c) {
    float mn = fminf(fminf(a, b), c);
    float sum = __expf((mn - a) * 10.0f) + __expf((mn - b) * 10.0f) + __expf((mn - c) * 10.0f);
    return mn - 0.1f * __logf(sum);
}

__device__ __forceinline__ void gld16(const void* g, void* l) {
    __builtin_amdgcn_global_load_lds(
        (const __attribute__((address_space(1))) unsigned int*)g,
        (__attribute__((address_space(3))) unsigned int*)l, 16, 0, 0);
}

// bf16 cell (a,b) of lane's 8x8 tile held in 8 uint4 registers -> fp32
__device__ __forceinline__ float cellf(const uint4* raw, int a, int b) {
    const unsigned* p = (const unsigned*)raw;
    unsigned wv = p[a * 4 + (b >> 1)];
    return __uint_as_float((b & 1) ? (wv & 0xffff0000u) : (wv << 16));
}

// OTAM DP over the lane's 8x8 tile (dir selects transpose), returns final cost
__device__ __forceinline__ float otam_dp(const uint4* raw, int dir) {
    float prev[10], cur[10];
    prev[0] = 0.f;
#pragma unroll
    for (int m = 1; m <= 8; m++) {
        float v0 = cellf(raw, 0, m - 1), v1 = cellf(raw, m - 1, 0);
        prev[m] = prev[m - 1] + (dir ? v1 : v0);
    }
    prev[9] = prev[8];
#pragma unroll
    for (int l = 1; l < 8; l++) {
        float d[8];
#pragma unroll
        for (int j = 0; j < 8; j++) {
            float v0 = cellf(raw, l, j), v1 = cellf(raw, j, l);
            d[j] = dir ? v1 : v0;
        }
        cur[1] = d[0] + softmin3(prev[0], prev[1], 0.0f);
#pragma unroll
        for (int m = 2; m <= 8; m++)
            cur[m] = d[m - 1] + softmin2(prev[m - 1], cur[m - 1]);
        cur[9] = softmin3(prev[8], prev[9], cur[8]);   // pad column: d=0
#pragma unroll
        for (int m = 1; m < 10; m++) prev[m] = cur[m];
    }
    return prev[9];
}

#define EBS (32 * 72)   // shorts per wave epilogue buffer: 32 rows x 64 cols pad 72

// ---------------- Kernel 2: fused GEMM (full 128x128 + 128x32 tail) + DP + class mean ----
// R7 = R0 structure (high co-residency: 896 blocks, ~3.5/CU, 18 KB LDS, 60 VGPR) +
//  (1) XOR slot swizzle on staging-source/ds-read pair (balances the b128 burst:
//      8-way -> minimum 8-deep; SQ_LDS_BANK_CONFLICT 6.8M -> ~0)
//  (2) XCD-chunked bijective grid swizzle (896%8==0): each XCD gets contiguous mt runs,
//      so the 7 nt-blocks sharing an A panel are temporally adjacent in its L2.
__global__ __launch_bounds__(256, 2) void gemm_kernel(
    const unsigned short* __restrict__ A,   // [MROWS][K] bf16 bits
    const unsigned short* __restrict__ B,   // [NPAD][K]  bf16 bits
    const float* __restrict__ nA, const float* __restrict__ nB,
    const int* __restrict__ labels,
    float* __restrict__ out)                // [QN][NCLS], zeroed by cvt
{
    __shared__ __align__(16) unsigned short smem[4 * EBS];   // 18432 B (staging aliases)
    unsigned short* Als = smem;             // 128*32 shorts
    unsigned short* Bls = smem + 4096;

    // ---- XCD-chunked grid swizzle: d -> (mt, nt), 896 work items, 8 XCDs x 112 ----
    const int d   = blockIdx.y * 128 + blockIdx.x;   // dispatch slot, XCD = d % 8
    const int s   = (d & 7) * 112 + (d >> 3);        // bijective (896 % 8 == 0)
    const int mt  = s / 7;            // 0..127  (consecutive s share mt -> same XCD)
    const int nt  = s % 7;            // 0..6 (6 = tail)
    const int tid = threadIdx.x;
    const int lane = tid & 63;
    const int w    = tid >> 6;
    const int col  = lane & 15, kg = lane >> 4;
    const int kgs  = kg ^ (col & 3);        // swizzled slot: every read row = base16+col
    const int mbase0 = mt * 128;

    const int c0 = tid, c1 = tid + 256;
    // staging source pre-swizzle: chunk c holds (row=c>>2, logical slot (c&3)^(row&3))
    const unsigned short* Ab0 = A + (size_t)(mbase0 + (c0 >> 2)) * KK + (((c0 & 3) ^ ((c0 >> 2) & 3)) * 8);
    const unsigned short* Ab1 = A + (size_t)(mbase0 + (c1 >> 2)) * KK + (((c1 & 3) ^ ((c1 >> 2) & 3)) * 8);

    if (nt < 6) {
        // ---------------- full 128x128 path ----------------
        const int wm = (w & 1) * 64, wn = (w >> 1) * 64;
        f32x4 acc[4][4] = {};
        const unsigned short* Bb0 = B + (size_t)(nt * 128 + (c0 >> 2)) * KK + (((c0 & 3) ^ ((c0 >> 2) & 3)) * 8);
        const unsigned short* Bb1 = B + (size_t)(nt * 128 + (c1 >> 2)) * KK + (((c1 & 3) ^ ((c1 >> 2) & 3)) * 8);

        for (int kk = 0; kk < KK; kk += 32) {
            __syncthreads();
            gld16(Ab0 + kk, (char*)Als + c0 * 16);
            gld16(Ab1 + kk, (char*)Als + c1 * 16);
            gld16(Bb0 + kk, (char*)Bls + c0 * 16);
            gld16(Bb1 + kk, (char*)Bls + c1 * 16);
            __syncthreads();
            bf16x8 af[4], bfr[4];
#pragma unroll
            for (int i = 0; i < 4; i++) af[i]  = *(const bf16x8*)(Als + (wm + i * 16 + col) * 32 + kgs * 8);
#pragma unroll
            for (int i = 0; i < 4; i++) bfr[i] = *(const bf16x8*)(Bls + (wn + i * 16 + col) * 32 + kgs * 8);
#pragma unroll
            for (int mi = 0; mi < 4; mi++)
#pragma unroll
                for (int ni = 0; ni < 4; ni++)
                    acc[mi][ni] = __builtin_amdgcn_mfma_f32_16x16x32_bf16(af[mi], bfr[ni], acc[mi][ni], 0, 0, 0);
        }

        __syncthreads();   // staging reads done (epilogue aliases)
        unsigned short* eb = smem + w * EBS;
        const int mbase = mbase0 + wm;
        const int nbase = nt * 128 + wn;
        const int pr  = lane & 31;
        const int qv2 = pr >> 3, sv = pr & 7;
        const int dir = lane >> 5;

#pragma unroll
        for (int p = 0; p < 2; p++) {
            if (p) __syncthreads();
#pragma unroll
            for (int mi2 = 0; mi2 < 2; mi2++) {
                const int mi = p * 2 + mi2;
                float nx[4];
#pragma unroll
                for (int r = 0; r < 4; r++) nx[r] = nA[mbase + mi * 16 + kg * 4 + r];
#pragma unroll
                for (int ni = 0; ni < 4; ni++) {
                    const float ny = nB[nbase + ni * 16 + col];
#pragma unroll
                    for (int r = 0; r < 4; r++) {
                        float d2 = 1.0f - acc[mi][ni][r] * __builtin_amdgcn_rcpf(nx[r] * ny + 0.01f);
                        eb[(mi2 * 16 + kg * 4 + r) * 72 + ni * 16 + col] = f2bf(d2);
                    }
                }
            }
            __syncthreads();

            uint4 raw[8];
            const unsigned short* tb = eb + (qv2 * 8) * 72 + sv * 8;
#pragma unroll
            for (int l = 0; l < 8; l++) raw[l] = *(const uint4*)(tb + l * 72);

            float res = otam_dp(raw, dir);
            res += __shfl_down(res, 32);
            if (dir == 0) {
                const int qg = mt * 16 + (wm >> 3) + p * 4 + qv2;
                const int sg = nt * 16 + (wn >> 3) + sv;
                atomicAdd(out + (size_t)qg * NCLS + labels[sg], -res * 0.2f);
            }
        }
    } else {
        // ---------------- 128x32 tail path (N cols 768..799) ----------------
        const int wm = w * 32;           // 4 waves cover 128 M-rows, all share 32 N-cols
        f32x4 acc[2][2] = {};
        const unsigned short* Bb0 = B + (size_t)(768 + (tid >> 2)) * KK + (((tid & 3) ^ ((tid >> 2) & 3)) * 8);  // tid<128

        for (int kk = 0; kk < KK; kk += 32) {
            __syncthreads();
            gld16(Ab0 + kk, (char*)Als + c0 * 16);
            gld16(Ab1 + kk, (char*)Als + c1 * 16);
            if (tid < 128) gld16(Bb0 + kk, (char*)Bls + tid * 16);
            __syncthreads();
            bf16x8 af[2], bfr[2];
#pragma unroll
            for (int i = 0; i < 2; i++) af[i]  = *(const bf16x8*)(Als + (wm + i * 16 + col) * 32 + kgs * 8);
#pragma unroll
            for (int i = 0; i < 2; i++) bfr[i] = *(const bf16x8*)(Bls + (i * 16 + col) * 32 + kgs * 8);
#pragma unroll
            for (int mi = 0; mi < 2; mi++)
#pragma unroll
                for (int ni = 0; ni < 2; ni++)
                    acc[mi][ni] = __builtin_amdgcn_mfma_f32_16x16x32_bf16(af[mi], bfr[ni], acc[mi][ni], 0, 0, 0);
        }

        __syncthreads();   // staging reads done
        unsigned short* eb = smem + w * EBS;   // 32 rows x 32 cols, stride 40 (1280 shorts used)
        const int mbase = mbase0 + wm;

#pragma unroll
        for (int mi = 0; mi < 2; mi++) {
            float nx[4];
#pragma unroll
            for (int r = 0; r < 4; r++) nx[r] = nA[mbase + mi * 16 + kg * 4 + r];
#pragma unroll
            for (int ni = 0; ni < 2; ni++) {
                const float ny = nB[768 + ni * 16 + col];
#pragma unroll
                for (int r = 0; r < 4; r++) {
                    float d2 = 1.0f - acc[mi][ni][r] * __builtin_amdgcn_rcpf(nx[r] * ny + 0.01f);
                    eb[(mi * 16 + kg * 4 + r) * 40 + ni * 16 + col] = f2bf(d2);
                }
            }
        }
        __syncthreads();

        // DP: 4 qv x 4 sv = 16 pairs x 2 dirs = 32 active lanes
        const int pr  = lane & 31;
        const int qv2 = (pr & 15) >> 2, sv = pr & 3;
        const int dir = lane >> 5;
        uint4 raw[8];
        const unsigned short* tb = eb + (qv2 * 8) * 40 + sv * 8;
#pragma unroll
        for (int l = 0; l < 8; l++) raw[l] = *(const uint4*)(tb + l * 40);

        float res = otam_dp(raw, dir);
        res += __shfl_down(res, 32);
        if (dir == 0 && pr < 16) {
            const int qg = mt * 16 + w * 4 + qv2;
            const int sg = 96 + sv;
            atomicAdd(out + (size_t)qg * NCLS + labels[sg], -res * 0.2f);
        }
    }
}

// ---------------- launch ----------------
extern "C" void kernel_launch(void* const* d_in, const int* in_sizes, int n_in,
                              void* d_out, int out_size, void* d_ws, size_t ws_size,
                              hipStream_t stream)
{
    const float* tf     = (const float*)d_in[0];   // [2048,8,2048] f32
    const float* sf     = (const float*)d_in[1];   // [100,8,2048]  f32
    const int*   labels = (const int*)d_in[2];     // [100] i32
    float* out = (float*)d_out;                    // [1,2048,20] f32

    char* ws = (char*)d_ws;
    const size_t szA    = (size_t)MROWS * KK * 2;      // 67108864
    const size_t szB    = (size_t)NPAD  * KK * 2;      // 3276800
    const size_t szNA   = (size_t)MROWS * 4;           // 65536
    unsigned short* Abf = (unsigned short*)ws;
    unsigned short* Bbf = (unsigned short*)(ws + szA);
    float* nA   = (float*)(ws + szA + szB);
    float* nB   = (float*)(ws + szA + szB + szNA);

    cvt_kernel<<<(MROWS + NPAD) / 4, 256, 0, stream>>>(tf, sf, Abf, Bbf, nA, nB, out);
    gemm_kernel<<<dim3(MROWS / 128, 7), 256, 0, stream>>>(Abf, Bbf, nA, nB, labels, out);
}

// Round 8
// 277.117 us; speedup vs baseline: 1.1747x; 1.0448x over previous
//
#include <hip/hip_runtime.h>

// Problem constants
#define QN    2048
#define SS    8
#define DD    2048
#define SP    100
#define NCLS  20
#define MROWS (QN*SS)       // 16384 GEMM M
#define NROWS (SP*SS)       // 800   logical N
#define NPAD  800           // no padding: 6 full 128-tiles + one 32-wide tail
#define KK    DD

typedef __bf16 bf16x8 __attribute__((ext_vector_type(8)));
typedef float  f32x4  __attribute__((ext_vector_type(4)));
typedef unsigned short ushort8 __attribute__((ext_vector_type(8)));

__device__ __forceinline__ unsigned short f2bf(float f) {
    unsigned int u = __float_as_uint(f);
    u += 0x7fffu + ((u >> 16) & 1u);   // round-to-nearest-even
    return (unsigned short)(u >> 16);
}

// ---------------- Kernel 1: fp32 -> bf16 + row L2 norms + out zeroing ----------------
// One WAVE per row (no barriers, no LDS). 4 rows per 256-thread block.
// R8: 16B stores (ushort8) + 32B loads per lane per iter -> half the memory instructions
// of the ushort4 version (G13: 16B/lane is the coalescing sweet spot).
__global__ void cvt_kernel(const float* __restrict__ tf, const float* __restrict__ sf,
                           unsigned short* __restrict__ Abf, unsigned short* __restrict__ Bbf,
                           float* __restrict__ nA, float* __restrict__ nB,
                           float* __restrict__ out)
{
    // zero the logits output (gemm accumulates atomically): 160*256 = 40960 elems
    if (blockIdx.x < 160) out[blockIdx.x * 256 + threadIdx.x] = 0.f;

    const int wv   = threadIdx.x >> 6;
    const int lane = threadIdx.x & 63;
    const int row  = blockIdx.x * 4 + wv;       // 0 .. 17183

    const float* src;
    unsigned short* dst;
    float* nrm; int r;
    if (row < MROWS) { src = tf + (size_t)row * DD; dst = Abf + (size_t)row * DD; nrm = nA; r = row; }
    else {
        r = row - MROWS;                        // 0..799, all real
        src = sf + (size_t)r * DD; dst = Bbf + (size_t)r * DD; nrm = nB;
    }

    float s = 0.f;
#pragma unroll
    for (int j = 0; j < 4; j++) {
        const float* p = src + j * 512 + lane * 8;
        float4 v0 = *(const float4*)(p);
        float4 v1 = *(const float4*)(p + 4);
        s += v0.x*v0.x + v0.y*v0.y + v0.z*v0.z + v0.w*v0.w;
        s += v1.x*v1.x + v1.y*v1.y + v1.z*v1.z + v1.w*v1.w;
        ushort8 pk;
        pk[0] = f2bf(v0.x); pk[1] = f2bf(v0.y); pk[2] = f2bf(v0.z); pk[3] = f2bf(v0.w);
        pk[4] = f2bf(v1.x); pk[5] = f2bf(v1.y); pk[6] = f2bf(v1.z); pk[7] = f2bf(v1.w);
        *(ushort8*)(dst + j * 512 + lane * 8) = pk;
    }
#pragma unroll
    for (int o = 32; o; o >>= 1) s += __shfl_down(s, o);
    if (lane == 0) nrm[r] = sqrtf(s);
}

// ---------------- softmin helpers ----------------
__device__ __forceinline__ float softmin2(float a, float b) {
    float mn = fminf(a, b), mx = fmaxf(a, b);
    return mn - 0.1f * __logf(1.0f + __expf((mn - mx) * 10.0f));
}
__device__ __forceinline__ float softmin3(float a, float b, float c) {
    float mn = fminf(fminf(a, b), c);
    float sum = __expf((mn - a) * 10.0f) + __expf((mn - b) * 10.0f) + __expf((mn - c) * 10.0f);
    return mn - 0.1f * __logf(sum);
}

__device__ __forceinline__ void gld16(const void* g, void* l) {
    __builtin_amdgcn_global_load_lds(
        (const __attribute__((address_space(1))) unsigned int*)g,
        (__attribute__((address_space(3))) unsigned int*)l, 16, 0, 0);
}

// bf16 cell (a,b) of lane's 8x8 tile held in 8 uint4 registers -> fp32
__device__ __forceinline__ float cellf(const uint4* raw, int a, int b) {
    const unsigned* p = (const unsigned*)raw;
    unsigned wv = p[a * 4 + (b >> 1)];
    return __uint_as_float((b & 1) ? (wv & 0xffff0000u) : (wv << 16));
}

// OTAM DP over the lane's 8x8 tile (dir selects transpose), returns final cost
__device__ __forceinline__ float otam_dp(const uint4* raw, int dir) {
    float prev[10], cur[10];
    prev[0] = 0.f;
#pragma unroll
    for (int m = 1; m <= 8; m++) {
        float v0 = cellf(raw, 0, m - 1), v1 = cellf(raw, m - 1, 0);
        prev[m] = prev[m - 1] + (dir ? v1 : v0);
    }
    prev[9] = prev[8];
#pragma unroll
    for (int l = 1; l < 8; l++) {
        float d[8];
#pragma unroll
        for (int j = 0; j < 8; j++) {
            float v0 = cellf(raw, l, j), v1 = cellf(raw, j, l);
            d[j] = dir ? v1 : v0;
        }
        cur[1] = d[0] + softmin3(prev[0], prev[1], 0.0f);
#pragma unroll
        for (int m = 2; m <= 8; m++)
            cur[m] = d[m - 1] + softmin2(prev[m - 1], cur[m - 1]);
        cur[9] = softmin3(prev[8], prev[9], cur[8]);   // pad column: d=0
#pragma unroll
        for (int m = 1; m < 10; m++) prev[m] = cur[m];
    }
    return prev[9];
}

#define EBS (32 * 72)   // shorts per wave epilogue buffer: 32 rows x 64 cols pad 72

// ---------------- Kernel 2: fused GEMM (full 128x128 + 128x32 tail) + DP + class mean ----
// EXACT R0 structure (best measured: 89.2 us profiled, 278.7/279.4 us bench).
__global__ __launch_bounds__(256, 2) void gemm_kernel(
    const unsigned short* __restrict__ A,   // [MROWS][K] bf16 bits
    const unsigned short* __restrict__ B,   // [NPAD][K]  bf16 bits
    const float* __restrict__ nA, const float* __restrict__ nB,
    const int* __restrict__ labels,
    float* __restrict__ out)                // [QN][NCLS], zeroed by cvt
{
    __shared__ __align__(16) unsigned short smem[4 * EBS];   // 18432 B (staging aliases)
    unsigned short* Als = smem;             // 128*32 shorts
    unsigned short* Bls = smem + 4096;

    const int mt  = blockIdx.x;      // 0..127
    const int nt  = blockIdx.y;      // 0..6 (6 = tail)
    const int tid = threadIdx.x;
    const int lane = tid & 63;
    const int w    = tid >> 6;
    const int col  = lane & 15, kg = lane >> 4;
    const int mbase0 = mt * 128;

    const int c0 = tid, c1 = tid + 256;
    const unsigned short* Ab0 = A + (size_t)(mbase0 + (c0 >> 2)) * KK + (c0 & 3) * 8;
    const unsigned short* Ab1 = A + (size_t)(mbase0 + (c1 >> 2)) * KK + (c1 & 3) * 8;

    if (nt < 6) {
        // ---------------- full 128x128 path (R5 config) ----------------
        const int wm = (w & 1) * 64, wn = (w >> 1) * 64;
        f32x4 acc[4][4] = {};
        const unsigned short* Bb0 = B + (size_t)(nt * 128 + (c0 >> 2)) * KK + (c0 & 3) * 8;
        const unsigned short* Bb1 = B + (size_t)(nt * 128 + (c1 >> 2)) * KK + (c1 & 3) * 8;

        for (int kk = 0; kk < KK; kk += 32) {
            __syncthreads();
            gld16(Ab0 + kk, (char*)Als + c0 * 16);
            gld16(Ab1 + kk, (char*)Als + c1 * 16);
            gld16(Bb0 + kk, (char*)Bls + c0 * 16);
            gld16(Bb1 + kk, (char*)Bls + c1 * 16);
            __syncthreads();
            bf16x8 af[4], bfr[4];
#pragma unroll
            for (int i = 0; i < 4; i++) af[i]  = *(const bf16x8*)(Als + (wm + i * 16 + col) * 32 + kg * 8);
#pragma unroll
            for (int i = 0; i < 4; i++) bfr[i] = *(const bf16x8*)(Bls + (wn + i * 16 + col) * 32 + kg * 8);
#pragma unroll
            for (int mi = 0; mi < 4; mi++)
#pragma unroll
                for (int ni = 0; ni < 4; ni++)
                    acc[mi][ni] = __builtin_amdgcn_mfma_f32_16x16x32_bf16(af[mi], bfr[ni], acc[mi][ni], 0, 0, 0);
        }

        __syncthreads();   // staging reads done (epilogue aliases)
        unsigned short* eb = smem + w * EBS;
        const int mbase = mbase0 + wm;
        const int nbase = nt * 128 + wn;
        const int pr  = lane & 31;
        const int qv2 = pr >> 3, sv = pr & 7;
        const int dir = lane >> 5;

#pragma unroll
        for (int p = 0; p < 2; p++) {
            if (p) __syncthreads();
#pragma unroll
            for (int mi2 = 0; mi2 < 2; mi2++) {
                const int mi = p * 2 + mi2;
                float nx[4];
#pragma unroll
                for (int r = 0; r < 4; r++) nx[r] = nA[mbase + mi * 16 + kg * 4 + r];
#pragma unroll
                for (int ni = 0; ni < 4; ni++) {
                    const float ny = nB[nbase + ni * 16 + col];
#pragma unroll
                    for (int r = 0; r < 4; r++) {
                        float d = 1.0f - acc[mi][ni][r] * __builtin_amdgcn_rcpf(nx[r] * ny + 0.01f);
                        eb[(mi2 * 16 + kg * 4 + r) * 72 + ni * 16 + col] = f2bf(d);
                    }
                }
            }
            __syncthreads();

            uint4 raw[8];
            const unsigned short* tb = eb + (qv2 * 8) * 72 + sv * 8;
#pragma unroll
            for (int l = 0; l < 8; l++) raw[l] = *(const uint4*)(tb + l * 72);

            float res = otam_dp(raw, dir);
            res += __shfl_down(res, 32);
            if (dir == 0) {
                const int qg = mt * 16 + (wm >> 3) + p * 4 + qv2;
                const int sg = nt * 16 + (wn >> 3) + sv;
                atomicAdd(out + (size_t)qg * NCLS + labels[sg], -res * 0.2f);
            }
        }
    } else {
        // ---------------- 128x32 tail path (N cols 768..799) ----------------
        const int wm = w * 32;           // 4 waves cover 128 M-rows, all share 32 N-cols
        f32x4 acc[2][2] = {};
        const unsigned short* Bb0 = B + (size_t)(768 + (tid >> 2)) * KK + (tid & 3) * 8;  // tid<128

        for (int kk = 0; kk < KK; kk += 32) {
            __syncthreads();
            gld16(Ab0 + kk, (char*)Als + c0 * 16);
            gld16(Ab1 + kk, (char*)Als + c1 * 16);
            if (tid < 128) gld16(Bb0 + kk, (char*)Bls + tid * 16);
            __syncthreads();
            bf16x8 af[2], bfr[2];
#pragma unroll
            for (int i = 0; i < 2; i++) af[i]  = *(const bf16x8*)(Als + (wm + i * 16 + col) * 32 + kg * 8);
#pragma unroll
            for (int i = 0; i < 2; i++) bfr[i] = *(const bf16x8*)(Bls + (i * 16 + col) * 32 + kg * 8);
#pragma unroll
            for (int mi = 0; mi < 2; mi++)
#pragma unroll
                for (int ni = 0; ni < 2; ni++)
                    acc[mi][ni] = __builtin_amdgcn_mfma_f32_16x16x32_bf16(af[mi], bfr[ni], acc[mi][ni], 0, 0, 0);
        }

        __syncthreads();   // staging reads done
        unsigned short* eb = smem + w * EBS;   // 32 rows x 32 cols, stride 40 (1280 shorts used)
        const int mbase = mbase0 + wm;

#pragma unroll
        for (int mi = 0; mi < 2; mi++) {
            float nx[4];
#pragma unroll
            for (int r = 0; r < 4; r++) nx[r] = nA[mbase + mi * 16 + kg * 4 + r];
#pragma unroll
            for (int ni = 0; ni < 2; ni++) {
                const float ny = nB[768 + ni * 16 + col];
#pragma unroll
                for (int r = 0; r < 4; r++) {
                    float d = 1.0f - acc[mi][ni][r] * __builtin_amdgcn_rcpf(nx[r] * ny + 0.01f);
                    eb[(mi * 16 + kg * 4 + r) * 40 + ni * 16 + col] = f2bf(d);
                }
            }
        }
        __syncthreads();

        // DP: 4 qv x 4 sv = 16 pairs x 2 dirs = 32 active lanes
        const int pr  = lane & 31;
        const int qv2 = (pr & 15) >> 2, sv = pr & 3;
        const int dir = lane >> 5;
        uint4 raw[8];
        const unsigned short* tb = eb + (qv2 * 8) * 40 + sv * 8;
#pragma unroll
        for (int l = 0; l < 8; l++) raw[l] = *(const uint4*)(tb + l * 40);

        float res = otam_dp(raw, dir);
        res += __shfl_down(res, 32);
        if (dir == 0 && pr < 16) {
            const int qg = mt * 16 + w * 4 + qv2;
            const int sg = 96 + sv;
            atomicAdd(out + (size_t)qg * NCLS + labels[sg], -res * 0.2f);
        }
    }
}

// ---------------- launch ----------------
extern "C" void kernel_launch(void* const* d_in, const int* in_sizes, int n_in,
                              void* d_out, int out_size, void* d_ws, size_t ws_size,
                              hipStream_t stream)
{
    const float* tf     = (const float*)d_in[0];   // [2048,8,2048] f32
    const float* sf     = (const float*)d_in[1];   // [100,8,2048]  f32
    const int*   labels = (const int*)d_in[2];     // [100] i32
    float* out = (float*)d_out;                    // [1,2048,20] f32

    char* ws = (char*)d_ws;
    const size_t szA    = (size_t)MROWS * KK * 2;      // 67108864
    const size_t szB    = (size_t)NPAD  * KK * 2;      // 3276800
    const size_t szNA   = (size_t)MROWS * 4;           // 65536
    unsigned short* Abf = (unsigned short*)ws;
    unsigned short* Bbf = (unsigned short*)(ws + szA);
    float* nA   = (float*)(ws + szA + szB);
    float* nB   = (float*)(ws + szA + szB + szNA);

    cvt_kernel<<<(MROWS + NPAD) / 4, 256, 0, stream>>>(tf, sf, Abf, Bbf, nA, nB, out);
    gemm_kernel<<<dim3(MROWS / 128, 7), 256, 0, stream>>>(Abf, Bbf, nA, nB, labels, out);
}